// Round 2
// baseline (877.960 us; speedup 1.0000x reference)
//
#include <hip/hip_runtime.h>
#include <math.h>

#define NS 2048
#define ND 1024
#define NK 256
#define NB 8

// ---------------- K0a: cosine table (2048 entries) + freq positions ----------------
__global__ void k_tab(float* __restrict__ tab, int* __restrict__ fposi) {
  int t = blockIdx.x * 256 + threadIdx.x;
  if (t < 2048) {
    double th = (double)t * (6.283185307179586476925286766559 / 2048.0);
    tab[t] = (float)cos(th);
  }
  if (t < 256) {
    // np.linspace(0, 512, 256): y_i = i*(512/255) in fp64, last forced to 512, trunc to int
    long f = (t == 255) ? 512 : (long)((double)t * (512.0 / 255.0));
    fposi[t] = (int)f;
  }
}

// ---------------- K0b: cw = mag*e^{i*phase} -> mc = mag*cos, ms = mag*sin ----------------
__global__ void k_cw(const float* __restrict__ mag, const float* __restrict__ ph,
                     float* __restrict__ mc, float* __restrict__ ms) {
  int i = blockIdx.x * 256 + threadIdx.x;  // 1024 blocks * 256 = 262144
  float m = mag[i], p = ph[i];
  float sp, cp;
  sincosf(p, &sp, &cp);
  mc[i] = m * cp;
  ms[i] = m * sp;
}

// ---------------- K1: forward DFT at 256 bins ----------------
// X[b,k,d] = sum_s x[b,s,d] * e^{-2pi i f_k s / 2048}
// grid 512 = 8b x 8kt(32 k each) x 8dt(128 d each); block 256.
// thread: dg = t&31 -> 4 consecutive d; kg = t>>5 -> 4 consecutive k.
__global__ __launch_bounds__(256)
void k1_dft(const float* __restrict__ x, const float* __restrict__ tab,
            const int* __restrict__ fposi, const float* __restrict__ mc,
            const float* __restrict__ ms, float* __restrict__ Xre,
            float* __restrict__ Xim, float* __restrict__ ReXw) {
  int bid = blockIdx.x;
  int dt = bid & 7, kt = (bid >> 3) & 7, b = bid >> 6;
  int t = threadIdx.x;
  int dg = t & 31, kg = t >> 5;
  int dloc = dg * 4;           // local d offset within 128-wide tile
  int d0 = dt * 128;
  int k0 = kt * 32 + kg * 4;

  __shared__ float tabs[2048];
  __shared__ float xs[32][128];
  for (int i = t; i < 2048; i += 256) tabs[i] = tab[i];

  int f[4], m[4];
#pragma unroll
  for (int j = 0; j < 4; j++) { f[j] = fposi[k0 + j]; m[j] = 0; }

  float ar[4][4] = {{0.f}}, ai[4][4] = {{0.f}};

  for (int sc = 0; sc < NS; sc += 32) {
    __syncthreads();
    const float* xb = x + ((size_t)b * NS + sc) * ND + d0;
    int si0 = t >> 5, col = (t & 31) * 4;
#pragma unroll
    for (int p = 0; p < 4; p++) {
      int si = si0 + p * 8;
      *(float4*)&xs[si][col] = *(const float4*)&xb[(size_t)si * ND + col];
    }
    __syncthreads();
#pragma unroll 8
    for (int si = 0; si < 32; si++) {
      float4 xv = *(float4*)&xs[si][dloc];
      float xvv[4] = {xv.x, xv.y, xv.z, xv.w};
#pragma unroll
      for (int j = 0; j < 4; j++) {
        float c = tabs[m[j]];
        float sn = tabs[(m[j] + 1536) & 2047];
#pragma unroll
        for (int q = 0; q < 4; q++) {
          ar[j][q] = fmaf(xvv[q], c, ar[j][q]);
          ai[j][q] = fmaf(xvv[q], sn, ai[j][q]);
        }
        m[j] = (m[j] + f[j]) & 2047;
      }
    }
  }

  // epilogue: Xre = sum x cos, Xim = -sum x sin; ReXw = Re(cw * X) = mc*Xre - ms*Xim
#pragma unroll
  for (int j = 0; j < 4; j++) {
    int k = k0 + j;
    size_t o = ((size_t)b * NK + k) * ND + d0 + dloc;
    const float4 mcv = *(const float4*)&mc[k * ND + d0 + dloc];
    const float4 msv = *(const float4*)&ms[k * ND + d0 + dloc];
    float xr[4], xi[4], rw[4];
    float mcc[4] = {mcv.x, mcv.y, mcv.z, mcv.w};
    float mss[4] = {msv.x, msv.y, msv.z, msv.w};
#pragma unroll
    for (int q = 0; q < 4; q++) {
      xr[q] = ar[j][q];
      xi[q] = -ai[j][q];
      rw[q] = mcc[q] * xr[q] - mss[q] * xi[q];
    }
    *(float4*)&Xre[o]  = make_float4(xr[0], xr[1], xr[2], xr[3]);
    *(float4*)&Xim[o]  = make_float4(xi[0], xi[1], xi[2], xi[3]);
    *(float4*)&ReXw[o] = make_float4(rw[0], rw[1], rw[2], rw[3]);
  }
}

// ---------------- K2: interference GEMM + delta epilogue ----------------
// I[b,j,d] = sum_k ReXw[b,k,d] * W[k,j]
// delta_re = alpha*((mc-1)*Xre - ms*Xim + 0.1*I); delta_im = alpha*(ms*Xre + (mc-1)*Xim)
// deltas overwrite Xre/Xim in place. alpha = (j==0 ? 1 : 2)/2048.
// grid 512 = 8b x 16jt(16 j) x 4dt(256 d); block 256: dg=t&63 -> 4 d; jg=t>>6 -> 4 j.
__global__ __launch_bounds__(256)
void k2_intf(const float* __restrict__ W, const float* __restrict__ ReXw,
             const float* __restrict__ mc, const float* __restrict__ ms,
             float* __restrict__ Xre, float* __restrict__ Xim) {
  int bid = blockIdx.x;
  int dt = bid & 3, jt = (bid >> 2) & 15, b = bid >> 6;
  int t = threadIdx.x;
  int dg = t & 63, jg = t >> 6;
  int d = dt * 256 + dg * 4;
  int j0 = jt * 16 + jg * 4;

  float acc[4][4] = {{0.f}};  // [j][d]
  const float* rx = ReXw + (size_t)b * (NK * ND) + d;
#pragma unroll 4
  for (int k = 0; k < NK; k++) {
    float4 rv = *(const float4*)(rx + (size_t)k * ND);
    float rvv[4] = {rv.x, rv.y, rv.z, rv.w};
#pragma unroll
    for (int jj = 0; jj < 4; jj++) {
      float w = W[k * NK + j0 + jj];
#pragma unroll
      for (int q = 0; q < 4; q++) acc[jj][q] = fmaf(rvv[q], w, acc[jj][q]);
    }
  }
#pragma unroll
  for (int jj = 0; jj < 4; jj++) {
    int j = j0 + jj;
    float alpha = ((j == 0) ? 1.0f : 2.0f) * (1.0f / (float)NS);
    size_t o = ((size_t)b * NK + j) * ND + d;
    float4 xrv = *(float4*)&Xre[o];
    float4 xiv = *(float4*)&Xim[o];
    const float4 mcv = *(const float4*)&mc[j * ND + d];
    const float4 msv = *(const float4*)&ms[j * ND + d];
    float xr[4] = {xrv.x, xrv.y, xrv.z, xrv.w};
    float xi[4] = {xiv.x, xiv.y, xiv.z, xiv.w};
    float mcc[4] = {mcv.x, mcv.y, mcv.z, mcv.w};
    float mss[4] = {msv.x, msv.y, msv.z, msv.w};
    float dre[4], dim[4];
#pragma unroll
    for (int q = 0; q < 4; q++) {
      float mc1 = mcc[q] - 1.0f;
      dre[q] = alpha * (mc1 * xr[q] - mss[q] * xi[q] + 0.1f * acc[jj][q]);
      dim[q] = alpha * (mss[q] * xr[q] + mc1 * xi[q]);
    }
    *(float4*)&Xre[o] = make_float4(dre[0], dre[1], dre[2], dre[3]);
    *(float4*)&Xim[o] = make_float4(dim[0], dim[1], dim[2], dim[3]);
  }
}

// ---------------- K3: synthesis ----------------
// corr[b,s,d] = sum_k ( dre[b,k,d]*cos(2pi f_k s/2048) - dim[b,k,d]*sin(...) )
// grid 4096 = 8b x 64st(32 s) x 8dt(128 d); block 256: dg=t&31 -> 4 d; sg=t>>5 -> 4 s.
__global__ __launch_bounds__(256)
void k3_syn(const float* __restrict__ dre, const float* __restrict__ dim_,
            const float* __restrict__ tab, const int* __restrict__ fposi,
            float* __restrict__ out) {
  int bid = blockIdx.x;
  int dt = bid & 7, st = (bid >> 3) & 63, b = bid >> 9;
  int t = threadIdx.x;
  int dg = t & 31, sg = t >> 5;
  int d0l = dg * 4;
  int d = dt * 128 + d0l;
  int sbase = st * 32 + sg * 4;

  __shared__ float tabs[2048];
  __shared__ int fs[256];
  __shared__ float rs[16][128], is_[16][128];
  for (int i = t; i < 2048; i += 256) tabs[i] = tab[i];
  if (t < 256) fs[t] = fposi[t];

  float acc[4][4] = {{0.f}};  // [s][d]

  for (int kc = 0; kc < NK; kc += 16) {
    __syncthreads();
    {
      int ki = t >> 5, col = (t & 31) * 4;
      const float* pr = dre  + ((size_t)b * NK + kc) * ND + dt * 128;
      const float* pi = dim_ + ((size_t)b * NK + kc) * ND + dt * 128;
#pragma unroll
      for (int p = 0; p < 2; p++) {
        int kk = ki + p * 8;
        *(float4*)&rs[kk][col]  = *(const float4*)&pr[(size_t)kk * ND + col];
        *(float4*)&is_[kk][col] = *(const float4*)&pi[(size_t)kk * ND + col];
      }
    }
    __syncthreads();
#pragma unroll 4
    for (int ki = 0; ki < 16; ki++) {
      int f = fs[kc + ki];
      float4 drv = *(float4*)&rs[ki][d0l];
      float4 div = *(float4*)&is_[ki][d0l];
      float drr[4] = {drv.x, drv.y, drv.z, drv.w};
      float dii[4] = {div.x, div.y, div.z, div.w};
#pragma unroll
      for (int jj = 0; jj < 4; jj++) {
        int s = sbase + jj;
        int mm = (f * s) & 2047;
        float c = tabs[mm];
        float sn = tabs[(mm + 1536) & 2047];
#pragma unroll
        for (int q = 0; q < 4; q++) {
          acc[jj][q] = fmaf(drr[q], c, acc[jj][q]);
          acc[jj][q] = fmaf(-dii[q], sn, acc[jj][q]);
        }
      }
    }
  }
#pragma unroll
  for (int jj = 0; jj < 4; jj++) {
    int s = sbase + jj;
    *(float4*)&out[((size_t)b * NS + s) * ND + d] =
        make_float4(acc[jj][0], acc[jj][1], acc[jj][2], acc[jj][3]);
  }
}

// ---------------- K4: y = 2x + corr, then LayerNorm over D ----------------
// grid 16384 rows; block 256; each thread owns 4 consecutive d (full row in regs).
__global__ __launch_bounds__(256)
void k4_ln(const float* __restrict__ x, const float* __restrict__ g,
           const float* __restrict__ be, float* __restrict__ out) {
  int row = blockIdx.x;
  int t = threadIdx.x;
  size_t base = (size_t)row * ND + t * 4;
  float4 cv = *(float4*)&out[base];
  float4 xv = *(const float4*)&x[base];
  float v[4] = {fmaf(2.f, xv.x, cv.x), fmaf(2.f, xv.y, cv.y),
                fmaf(2.f, xv.z, cv.z), fmaf(2.f, xv.w, cv.w)};
  float s = v[0] + v[1] + v[2] + v[3];
  float q = v[0]*v[0] + v[1]*v[1] + v[2]*v[2] + v[3]*v[3];
#pragma unroll
  for (int o = 32; o >= 1; o >>= 1) {
    s += __shfl_xor(s, o, 64);
    q += __shfl_xor(q, o, 64);
  }
  __shared__ float ss[4], qs[4];
  if ((t & 63) == 0) { ss[t >> 6] = s; qs[t >> 6] = q; }
  __syncthreads();
  s = ss[0] + ss[1] + ss[2] + ss[3];
  q = qs[0] + qs[1] + qs[2] + qs[3];
  float mu = s * (1.0f / (float)ND);
  float var = q * (1.0f / (float)ND) - mu * mu;
  float rstd = rsqrtf(var + 1e-5f);
  float4 gv = *(const float4*)&g[t * 4];
  float4 bv = *(const float4*)&be[t * 4];
  float4 ov;
  ov.x = (v[0] - mu) * rstd * gv.x + bv.x;
  ov.y = (v[1] - mu) * rstd * gv.y + bv.y;
  ov.z = (v[2] - mu) * rstd * gv.z + bv.z;
  ov.w = (v[3] - mu) * rstd * gv.w + bv.w;
  *(float4*)&out[base] = ov;
}

extern "C" void kernel_launch(void* const* d_in, const int* in_sizes, int n_in,
                              void* d_out, int out_size, void* d_ws, size_t ws_size,
                              hipStream_t stream) {
  const float* x   = (const float*)d_in[0];
  const float* mag = (const float*)d_in[1];
  const float* ph  = (const float*)d_in[2];
  const float* W   = (const float*)d_in[3];
  const float* g   = (const float*)d_in[4];
  const float* be  = (const float*)d_in[5];
  float* out = (float*)d_out;
  float* ws  = (float*)d_ws;

  // ws layout (floats): tab[2048] | fposi[256 ints] | mc[256*1024] | ms[256*1024]
  //                     | Xre[8*256*1024] | Xim[8*256*1024]   (~18.9 MB)
  float* tab   = ws;
  int*   fposi = (int*)(ws + 2048);
  float* mc    = ws + 4096;
  float* ms    = mc + (size_t)NK * ND;
  float* Xre   = ms + (size_t)NK * ND;
  float* Xim   = Xre + (size_t)NB * NK * ND;
  // ReXw staged in d_out (first 8 MB); overwritten later by K3 after K2 consumed it.
  float* ReXw  = out;

  k_tab<<<8, 256, 0, stream>>>(tab, fposi);
  k_cw<<<1024, 256, 0, stream>>>(mag, ph, mc, ms);
  k1_dft<<<512, 256, 0, stream>>>(x, tab, fposi, mc, ms, Xre, Xim, ReXw);
  k2_intf<<<512, 256, 0, stream>>>(W, ReXw, mc, ms, Xre, Xim);
  k3_syn<<<4096, 256, 0, stream>>>(Xre, Xim, tab, fposi, out);
  k4_ln<<<16384, 256, 0, stream>>>(x, g, be, out);
}

// Round 3
// 242.312 us; speedup vs baseline: 3.6233x; 3.6233x over previous
//
#include <hip/hip_runtime.h>
#include <math.h>

#define NS 2048
#define ND 1024
#define NK 256
#define NB 8

typedef __attribute__((ext_vector_type(8))) short short8;
typedef __attribute__((ext_vector_type(4))) float f32x4;
typedef __attribute__((ext_vector_type(4))) unsigned short u16x4;
typedef __attribute__((ext_vector_type(8))) unsigned short u16x8;

__device__ __forceinline__ unsigned short f2bf(float x) {
  unsigned int u = __float_as_uint(x);
  u = (u + 0x7fffu + ((u >> 16) & 1u)) >> 16;
  return (unsigned short)u;
}
__device__ __forceinline__ float bf2f(unsigned short h) {
  return __uint_as_float(((unsigned int)h) << 16);
}

__device__ __forceinline__ int fpos(int k) {
  // np.linspace(0, 512, 256).astype(int64): exact integers only at k=0,255;
  // elsewhere distance to integer >= 0.0078 >> fp32 eps -> fp32 floor safe.
  return (k == 255) ? 512 : (int)((float)k * (512.0f / 255.0f));
}

// ---------------- K0a: bf16 trig tables ----------------
// CF [512][2048]: rows 0..255 = cos(2pi f_k s/2048), rows 256..511 = -sin(...)
// CS [2048][512]: cols 0..255 = cos, cols 256..511 = -sin
__global__ __launch_bounds__(256) void k_tab(unsigned short* __restrict__ CF,
                                             unsigned short* __restrict__ CS) {
  int gid = blockIdx.x * 256 + threadIdx.x;  // 8192 blocks -> 2*1048576
  if (gid < 512 * 2048) {
    int m = gid >> 11, s = gid & 2047;
    int ph = (fpos(m & 255) * s) & 2047;
    float th = (float)ph * 0.0030679615757712823f;  // 2pi/2048
    float v = (m < 256) ? cosf(th) : -sinf(th);
    CF[gid] = f2bf(v);
  } else {
    int g = gid - 512 * 2048;
    int s = g >> 9, kk = g & 511;
    int ph = (fpos(kk & 255) * s) & 2047;
    float th = (float)ph * 0.0030679615757712823f;
    float v = (kk < 256) ? cosf(th) : -sinf(th);
    CS[g] = f2bf(v);
  }
}

// ---------------- K0b: mc = mag*cos(phase), ms = mag*sin(phase) (fp32) ----------------
__global__ __launch_bounds__(256) void k_cw(const float* __restrict__ mag,
                                            const float* __restrict__ ph,
                                            float* __restrict__ mc,
                                            float* __restrict__ ms) {
  int i = blockIdx.x * 256 + threadIdx.x;  // 1024 blocks
  float m = mag[i], p = ph[i];
  float sp, cp;
  sincosf(p, &sp, &cp);
  mc[i] = m * cp;
  ms[i] = m * sp;
}

// ---------------- conv: x fp32 [b][s][d] -> x_t bf16 [b][d][s] ----------------
__global__ __launch_bounds__(256) void k_conv(const float* __restrict__ x,
                                              unsigned short* __restrict__ xt) {
  int bid = blockIdx.x;  // 8b * 32st * 16dt = 4096
  int b = bid >> 9, rem = bid & 511;
  int s0 = (rem >> 4) * 64, d0 = (rem & 15) * 64;
  int t = threadIdx.x;
  __shared__ __attribute__((aligned(16))) unsigned short lt[64 * 72];  // [d][s+pad]
#pragma unroll
  for (int c = 0; c < 4; c++) {
    int e = c * 256 + t;
    int row = e >> 4, col = (e & 15) * 4;  // row: s-local, col: d-local
    float4 v = *(const float4*)&x[((size_t)b * NS + s0 + row) * ND + d0 + col];
    lt[(col + 0) * 72 + row] = f2bf(v.x);
    lt[(col + 1) * 72 + row] = f2bf(v.y);
    lt[(col + 2) * 72 + row] = f2bf(v.z);
    lt[(col + 3) * 72 + row] = f2bf(v.w);
  }
  __syncthreads();
  int dl = t >> 2, sc = (t & 3) * 16;
  u16x8 a = *(u16x8*)&lt[dl * 72 + sc];
  u16x8 bb = *(u16x8*)&lt[dl * 72 + sc + 8];
  size_t o = ((size_t)b * ND + d0 + dl) * NS + s0 + sc;
  *(u16x8*)&xt[o] = a;
  *(u16x8*)&xt[o + 8] = bb;
}

// ---------------- MFMA GEMM: C[b][M][N] = A[M][K] * B[b][N][K]^T ----------------
// bf16 inputs, fp32 accum. 256 thr = 4 waves (2x2), 16x16x32 MFMA, BK=64.
// LDS tiles [rows][64] bf16 with slot^=(row&7) XOR swizzle (T2) on write+read.
// T14 prefetch: next tile's global loads issue before current barrier.
template <int BM, int BN, int OUTBF>
__global__ __launch_bounds__(256) void gemm_tt(const unsigned short* __restrict__ A,
                                               const unsigned short* __restrict__ B,
                                               void* __restrict__ C,
                                               int M, int N, int K) {
  constexpr int MI = BM / 32, NI = BN / 32;
  constexpr int ACH = BM / 32, BCH = BN / 32;
  const int mt = M / BM, nt = N / BN;
  int bid = blockIdx.x;
  int b = bid / (mt * nt);
  int r = bid % (mt * nt);
  int m0 = (r / nt) * BM, n0 = (r % nt) * BN;
  int t = threadIdx.x, lane = t & 63;
  int wr = (t >> 7) & 1, wc = (t >> 6) & 1;
  __shared__ __attribute__((aligned(16))) unsigned short As[BM * 64];
  __shared__ __attribute__((aligned(16))) unsigned short Bs[BN * 64];

  const unsigned short* Ag = A + (size_t)m0 * K;
  const unsigned short* Bg = B + ((size_t)b * N + n0) * K;

  f32x4 acc[MI][NI];
#pragma unroll
  for (int i = 0; i < MI; i++)
#pragma unroll
    for (int j = 0; j < NI; j++) acc[i][j] = {0.f, 0.f, 0.f, 0.f};

  short8 la[ACH], lb[BCH], na[ACH], nb[BCH];

#pragma unroll
  for (int c = 0; c < ACH; c++) {
    int e = c * 256 + t, row = e >> 3, sl = e & 7;
    la[c] = *(const short8*)&Ag[(size_t)row * K + sl * 8];
  }
#pragma unroll
  for (int c = 0; c < BCH; c++) {
    int e = c * 256 + t, row = e >> 3, sl = e & 7;
    lb[c] = *(const short8*)&Bg[(size_t)row * K + sl * 8];
  }

  const int nkt = K / 64;
  for (int kt = 0; kt < nkt; ++kt) {
    if (kt + 1 < nkt) {  // prefetch next tile (in flight across barriers+compute)
      int k0 = (kt + 1) * 64;
#pragma unroll
      for (int c = 0; c < ACH; c++) {
        int e = c * 256 + t, row = e >> 3, sl = e & 7;
        na[c] = *(const short8*)&Ag[(size_t)row * K + k0 + sl * 8];
      }
#pragma unroll
      for (int c = 0; c < BCH; c++) {
        int e = c * 256 + t, row = e >> 3, sl = e & 7;
        nb[c] = *(const short8*)&Bg[(size_t)row * K + k0 + sl * 8];
      }
    }
    __syncthreads();
#pragma unroll
    for (int c = 0; c < ACH; c++) {
      int e = c * 256 + t, row = e >> 3, sl = e & 7;
      *(short8*)&As[row * 64 + ((sl ^ (row & 7)) * 8)] = la[c];
    }
#pragma unroll
    for (int c = 0; c < BCH; c++) {
      int e = c * 256 + t, row = e >> 3, sl = e & 7;
      *(short8*)&Bs[row * 64 + ((sl ^ (row & 7)) * 8)] = lb[c];
    }
    __syncthreads();
#pragma unroll
    for (int ks = 0; ks < 2; ks++) {
      short8 af[MI], bfr[NI];
#pragma unroll
      for (int mi = 0; mi < MI; mi++) {
        int rowl = wr * (BM / 2) + mi * 16 + (lane & 15);
        int sl = ks * 4 + (lane >> 4);
        af[mi] = *(const short8*)&As[rowl * 64 + ((sl ^ (rowl & 7)) * 8)];
      }
#pragma unroll
      for (int ni = 0; ni < NI; ni++) {
        int rowl = wc * (BN / 2) + ni * 16 + (lane & 15);
        int sl = ks * 4 + (lane >> 4);
        bfr[ni] = *(const short8*)&Bs[rowl * 64 + ((sl ^ (rowl & 7)) * 8)];
      }
#pragma unroll
      for (int mi = 0; mi < MI; mi++)
#pragma unroll
        for (int ni = 0; ni < NI; ni++)
          acc[mi][ni] = __builtin_amdgcn_mfma_f32_16x16x32_bf16(
              af[mi], bfr[ni], acc[mi][ni], 0, 0, 0);
    }
#pragma unroll
    for (int c = 0; c < ACH; c++) la[c] = na[c];
#pragma unroll
    for (int c = 0; c < BCH; c++) lb[c] = nb[c];
  }

  // epilogue: C/D layout col=lane&15, row=(lane>>4)*4+q  [m89-verified]
#pragma unroll
  for (int mi = 0; mi < MI; mi++) {
#pragma unroll
    for (int ni = 0; ni < NI; ni++) {
      int row0 = m0 + wr * (BM / 2) + mi * 16 + ((lane >> 4) * 4);
      int col = n0 + wc * (BN / 2) + ni * 16 + (lane & 15);
#pragma unroll
      for (int q = 0; q < 4; q++) {
        size_t o = ((size_t)b * M + row0 + q) * (size_t)N + col;
        if (OUTBF)
          ((unsigned short*)C)[o] = f2bf(acc[mi][ni][q]);
        else
          ((float*)C)[o] = acc[mi][ni][q];
      }
    }
  }
}

// ---------------- k1b: ReXw = mc*Xre - ms*Xim  (bf16 out) ----------------
__global__ __launch_bounds__(256) void k1b(const unsigned short* __restrict__ Xq,
                                           const float* __restrict__ mc,
                                           const float* __restrict__ ms,
                                           unsigned short* __restrict__ RXw) {
  int e8 = blockIdx.x * 256 + threadIdx.x;  // 1024 blocks -> 262144 * 8 elems
  int d8 = (e8 & 127) * 8;
  int rowg = e8 >> 7;  // b*256 + k
  int b = rowg >> 8, k = rowg & 255;
  u16x8 re = *(const u16x8*)&Xq[((size_t)b * 512 + k) * ND + d8];
  u16x8 im = *(const u16x8*)&Xq[((size_t)b * 512 + 256 + k) * ND + d8];
  u16x8 o;
#pragma unroll
  for (int q = 0; q < 8; q++) {
    float mcv = mc[k * ND + d8 + q], msv = ms[k * ND + d8 + q];
    o[q] = f2bf(mcv * bf2f(re[q]) - msv * bf2f(im[q]));
  }
  *(u16x8*)&RXw[(size_t)rowg * ND + d8] = o;
}

// ---------------- K2: I = W^T x ReXw, deltas, write transposed ----------------
// grid 8b * 4jt * 16dt = 512. Block: 64 j x 64 d. Thread: 4 j x 4 d.
__global__ __launch_bounds__(256) void k2_intf(const float* __restrict__ W,
                                               const unsigned short* __restrict__ RXw,
                                               const unsigned short* __restrict__ Xq,
                                               const float* __restrict__ mc,
                                               const float* __restrict__ ms,
                                               unsigned short* __restrict__ DltT) {
  int bid = blockIdx.x;
  int b = bid >> 6, rem = bid & 63;
  int jt = rem >> 4, dt = rem & 15;
  int t = threadIdx.x;
  int tj = t >> 4, td = t & 15;
  __shared__ __attribute__((aligned(16))) unsigned short Rx[256 * 64];  // [k][d]
  __shared__ __attribute__((aligned(16))) unsigned short Wl[256 * 64];  // [k][j]
#pragma unroll
  for (int c = 0; c < 8; c++) {
    int e = c * 256 + t, row = e >> 3, col = (e & 7) * 8;
    *(u16x8*)&Rx[row * 64 + col] =
        *(const u16x8*)&RXw[((size_t)b * NK + row) * ND + dt * 64 + col];
  }
#pragma unroll
  for (int c = 0; c < 16; c++) {
    int e = c * 256 + t, row = e >> 4, col = (e & 15) * 4;
    float4 w = *(const float4*)&W[row * NK + jt * 64 + col];
    u16x4 wv = {f2bf(w.x), f2bf(w.y), f2bf(w.z), f2bf(w.w)};
    *(u16x4*)&Wl[row * 64 + col] = wv;
  }
  __syncthreads();
  float acc[4][4];  // [jj][qd]
#pragma unroll
  for (int i = 0; i < 4; i++)
#pragma unroll
    for (int j = 0; j < 4; j++) acc[i][j] = 0.f;
#pragma unroll 4
  for (int k = 0; k < 256; k++) {
    u16x4 r4 = *(const u16x4*)&Rx[k * 64 + td * 4];
    u16x4 w4 = *(const u16x4*)&Wl[k * 64 + tj * 4];
    float rf[4] = {bf2f(r4[0]), bf2f(r4[1]), bf2f(r4[2]), bf2f(r4[3])};
    float wf[4] = {bf2f(w4[0]), bf2f(w4[1]), bf2f(w4[2]), bf2f(w4[3])};
#pragma unroll
    for (int jj = 0; jj < 4; jj++)
#pragma unroll
      for (int q = 0; q < 4; q++) acc[jj][q] = fmaf(wf[jj], rf[q], acc[jj][q]);
  }
  int jbase = jt * 64 + tj * 4;  // wait: jt*64? block j-range is 64 -> jbase within [0,256)
  jbase = jt * 64 + tj * 4;
  int dg = dt * 64 + td * 4;
  float dre[4][4], dim[4][4];
#pragma unroll
  for (int jj = 0; jj < 4; jj++) {
    int j = jbase + jj;
    float alpha = ((j == 0) ? 1.0f : 2.0f) * (1.0f / 2048.0f);
    u16x4 re4 = *(const u16x4*)&Xq[((size_t)b * 512 + j) * ND + dg];
    u16x4 im4 = *(const u16x4*)&Xq[((size_t)b * 512 + 256 + j) * ND + dg];
    float4 mc4 = *(const float4*)&mc[j * ND + dg];
    float4 ms4 = *(const float4*)&ms[j * ND + dg];
    float mcc[4] = {mc4.x, mc4.y, mc4.z, mc4.w};
    float mss[4] = {ms4.x, ms4.y, ms4.z, ms4.w};
#pragma unroll
    for (int q = 0; q < 4; q++) {
      float xr = bf2f(re4[q]), xi = bf2f(im4[q]);
      float m1 = mcc[q] - 1.0f;
      dre[jj][q] = alpha * (m1 * xr - mss[q] * xi + 0.1f * acc[jj][q]);
      dim[jj][q] = alpha * (mss[q] * xr + m1 * xi);
    }
  }
#pragma unroll
  for (int q = 0; q < 4; q++) {
    u16x4 vr = {f2bf(dre[0][q]), f2bf(dre[1][q]), f2bf(dre[2][q]), f2bf(dre[3][q])};
    u16x4 vi = {f2bf(dim[0][q]), f2bf(dim[1][q]), f2bf(dim[2][q]), f2bf(dim[3][q])};
    size_t rowo = ((size_t)b * ND + dg + q) * 512;
    *(u16x4*)&DltT[rowo + jbase] = vr;
    *(u16x4*)&DltT[rowo + 256 + jbase] = vi;
  }
}

// ---------------- K4: y = 2x + corr, LayerNorm over D ----------------
__global__ __launch_bounds__(256) void k4_ln(const float* __restrict__ x,
                                             const float* __restrict__ g,
                                             const float* __restrict__ be,
                                             float* __restrict__ out) {
  int row = blockIdx.x;
  int t = threadIdx.x;
  size_t base = (size_t)row * ND + t * 4;
  float4 cv = *(float4*)&out[base];
  float4 xv = *(const float4*)&x[base];
  float v[4] = {fmaf(2.f, xv.x, cv.x), fmaf(2.f, xv.y, cv.y),
                fmaf(2.f, xv.z, cv.z), fmaf(2.f, xv.w, cv.w)};
  float s = v[0] + v[1] + v[2] + v[3];
  float q = v[0] * v[0] + v[1] * v[1] + v[2] * v[2] + v[3] * v[3];
#pragma unroll
  for (int o = 32; o >= 1; o >>= 1) {
    s += __shfl_xor(s, o, 64);
    q += __shfl_xor(q, o, 64);
  }
  __shared__ float ss[4], qs[4];
  if ((t & 63) == 0) { ss[t >> 6] = s; qs[t >> 6] = q; }
  __syncthreads();
  s = ss[0] + ss[1] + ss[2] + ss[3];
  q = qs[0] + qs[1] + qs[2] + qs[3];
  float mu = s * (1.0f / (float)ND);
  float var = q * (1.0f / (float)ND) - mu * mu;
  float rstd = rsqrtf(var + 1e-5f);
  float4 gv = *(const float4*)&g[t * 4];
  float4 bv = *(const float4*)&be[t * 4];
  float4 ov;
  ov.x = (v[0] - mu) * rstd * gv.x + bv.x;
  ov.y = (v[1] - mu) * rstd * gv.y + bv.y;
  ov.z = (v[2] - mu) * rstd * gv.z + bv.z;
  ov.w = (v[3] - mu) * rstd * gv.w + bv.w;
  *(float4*)&out[base] = ov;
}

extern "C" void kernel_launch(void* const* d_in, const int* in_sizes, int n_in,
                              void* d_out, int out_size, void* d_ws, size_t ws_size,
                              hipStream_t stream) {
  const float* x   = (const float*)d_in[0];
  const float* mag = (const float*)d_in[1];
  const float* ph  = (const float*)d_in[2];
  const float* W   = (const float*)d_in[3];
  const float* g   = (const float*)d_in[4];
  const float* be  = (const float*)d_in[5];
  float* out = (float*)d_out;
  char* o = (char*)d_out;
  char* w = (char*)d_ws;

  // ws (14 MB): CF 2MB | CS 2MB | mc 1MB | ms 1MB | DltT 8MB
  unsigned short* CF  = (unsigned short*)w;
  unsigned short* CS  = (unsigned short*)(w + (2u << 20));
  float* mc           = (float*)(w + (4u << 20));
  float* ms           = (float*)(w + (5u << 20));
  unsigned short* Dlt = (unsigned short*)(w + (6u << 20));
  // d_out scratch (consumed before K3 overwrites with corr):
  unsigned short* xt  = (unsigned short*)o;               // 32 MB  [b][d][s]
  unsigned short* Xq  = (unsigned short*)(o + (32u << 20));  // 8 MB [b][512][d]
  unsigned short* RXw = (unsigned short*)(o + (40u << 20));  // 4 MB [b][256][d]

  k_tab<<<8192, 256, 0, stream>>>(CF, CS);
  k_cw<<<1024, 256, 0, stream>>>(mag, ph, mc, ms);
  k_conv<<<4096, 256, 0, stream>>>(x, xt);
  gemm_tt<128, 64, 1><<<512, 256, 0, stream>>>(CF, xt, Xq, 512, 1024, 2048);
  k1b<<<1024, 256, 0, stream>>>(Xq, mc, ms, RXw);
  k2_intf<<<512, 256, 0, stream>>>(W, RXw, Xq, mc, ms, Dlt);
  gemm_tt<128, 128, 0><<<1024, 256, 0, stream>>>(CS, Dlt, out, 2048, 1024, 512);
  k4_ln<<<16384, 256, 0, stream>>>(x, g, be, out);
}

// Round 4
// 239.450 us; speedup vs baseline: 3.6666x; 1.0120x over previous
//
#include <hip/hip_runtime.h>
#include <math.h>

#define NS 2048
#define ND 1024
#define NK 256
#define NB 8

typedef __attribute__((ext_vector_type(8))) short short8;
typedef __attribute__((ext_vector_type(4))) float f32x4;
typedef __attribute__((ext_vector_type(4))) unsigned short u16x4;
typedef __attribute__((ext_vector_type(8))) unsigned short u16x8;

__device__ __forceinline__ unsigned short f2bf(float x) {
  unsigned int u = __float_as_uint(x);
  u = (u + 0x7fffu + ((u >> 16) & 1u)) >> 16;
  return (unsigned short)u;
}
__device__ __forceinline__ float bf2f(unsigned short h) {
  return __uint_as_float(((unsigned int)h) << 16);
}

__device__ __forceinline__ int fpos(int k) {
  // np.linspace(0, 512, 256).astype(int64): fp64 i*512/255 truncated; fp32 safe
  // (distance to integer >= 0.0078 except exact endpoints).
  return (k == 255) ? 512 : (int)((float)k * (512.0f / 255.0f));
}

// async global->LDS, 16B per lane. LDS dest is wave-uniform base + lane*16.
__device__ __forceinline__ void gll16(const unsigned short* g, unsigned short* l) {
  __builtin_amdgcn_global_load_lds(
      (__attribute__((address_space(1))) void*)(void*)const_cast<unsigned short*>(g),
      (__attribute__((address_space(3))) void*)l, 16, 0, 0);
}

// ---------------- K0a: bf16 trig tables ----------------
// CF [512][2048]: rows 0..255 = cos(2pi f_k s/2048), rows 256..511 = -sin
// CS [2048][512]: cols 0..255 = cos, cols 256..511 = -sin
__global__ __launch_bounds__(256) void k_tab(unsigned short* __restrict__ CF,
                                             unsigned short* __restrict__ CS) {
  int gid = blockIdx.x * 256 + threadIdx.x;  // 8192 blocks
  if (gid < 512 * 2048) {
    int m = gid >> 11, s = gid & 2047;
    int ph = (fpos(m & 255) * s) & 2047;
    float th = (float)ph * 0.0030679615757712823f;  // 2pi/2048
    float v = (m < 256) ? cosf(th) : -sinf(th);
    CF[gid] = f2bf(v);
  } else {
    int g = gid - 512 * 2048;
    int s = g >> 9, kk = g & 511;
    int ph = (fpos(kk & 255) * s) & 2047;
    float th = (float)ph * 0.0030679615757712823f;
    float v = (kk < 256) ? cosf(th) : -sinf(th);
    CS[g] = f2bf(v);
  }
}

// ---------------- k_cwT: mcT[d][k]=mag*cos(phase), msT[d][k]=mag*sin (fp32, transposed) ----
__global__ __launch_bounds__(256) void k_cwT(const float* __restrict__ mag,
                                             const float* __restrict__ ph,
                                             float* __restrict__ mcT,
                                             float* __restrict__ msT) {
  int bid = blockIdx.x;  // 64 = 4 ktile x 16 dtile, each 64k x 64d
  int kt = bid >> 4, dt = bid & 15;
  int t = threadIdx.x;
  __shared__ float lc[64][68], ls[64][68];
  int kl = t >> 4, d4 = (t & 15) * 4;
#pragma unroll
  for (int i = 0; i < 4; i++) {
    int k = i * 16 + kl;
    size_t off = (size_t)(kt * 64 + k) * ND + dt * 64 + d4;
    float4 mg = *(const float4*)&mag[off];
    float4 pp = *(const float4*)&ph[off];
    float m[4] = {mg.x, mg.y, mg.z, mg.w}, p[4] = {pp.x, pp.y, pp.z, pp.w};
#pragma unroll
    for (int q = 0; q < 4; q++) {
      float sp, cp;
      sincosf(p[q], &sp, &cp);
      lc[k][d4 + q] = m[q] * cp;
      ls[k][d4 + q] = m[q] * sp;
    }
  }
  __syncthreads();
  int dl = t >> 2, kc = (t & 3) * 16;
#pragma unroll
  for (int i = 0; i < 16; i += 4) {
    float4 vc = {lc[kc + i][dl], lc[kc + i + 1][dl], lc[kc + i + 2][dl], lc[kc + i + 3][dl]};
    float4 vs = {ls[kc + i][dl], ls[kc + i + 1][dl], ls[kc + i + 2][dl], ls[kc + i + 3][dl]};
    size_t o = (size_t)(dt * 64 + dl) * 256 + kt * 64 + kc + i;
    *(float4*)&mcT[o] = vc;
    *(float4*)&msT[o] = vs;
  }
}

// ---------------- k_wt: WT[j][k] bf16 = W[k][j] ----------------
__global__ __launch_bounds__(256) void k_wt(const float* __restrict__ W,
                                            unsigned short* __restrict__ WT) {
  int bid = blockIdx.x;  // 16 = 4 kt x 4 jt
  int kt = bid >> 2, jt = bid & 3;
  int t = threadIdx.x;
  __shared__ float lw[64][68];
  int kl = t >> 4, j4 = (t & 15) * 4;
#pragma unroll
  for (int i = 0; i < 4; i++) {
    int k = i * 16 + kl;
    float4 wv = *(const float4*)&W[(size_t)(kt * 64 + k) * 256 + jt * 64 + j4];
    lw[k][j4 + 0] = wv.x; lw[k][j4 + 1] = wv.y;
    lw[k][j4 + 2] = wv.z; lw[k][j4 + 3] = wv.w;
  }
  __syncthreads();
  int jl = t >> 2, kc = (t & 3) * 16;
#pragma unroll
  for (int i = 0; i < 16; i += 4) {
    u16x4 v = {f2bf(lw[kc + i][jl]), f2bf(lw[kc + i + 1][jl]),
               f2bf(lw[kc + i + 2][jl]), f2bf(lw[kc + i + 3][jl])};
    *(u16x4*)&WT[(size_t)(jt * 64 + jl) * 256 + kt * 64 + kc + i] = v;
  }
}

// ---------------- conv: x fp32 [b][s][d] -> xt bf16 [b][d][s] ----------------
__global__ __launch_bounds__(256) void k_conv(const float* __restrict__ x,
                                              unsigned short* __restrict__ xt) {
  int bid = blockIdx.x;  // 8b * 32st * 16dt = 4096
  int b = bid >> 9, rem = bid & 511;
  int s0 = (rem >> 4) * 64, d0 = (rem & 15) * 64;
  int t = threadIdx.x;
  __shared__ __attribute__((aligned(16))) unsigned short lt[64 * 72];  // [d][s+pad]
#pragma unroll
  for (int c = 0; c < 4; c++) {
    int e = c * 256 + t;
    int row = e >> 4, col = (e & 15) * 4;  // row: s-local, col: d-local
    float4 v = *(const float4*)&x[((size_t)b * NS + s0 + row) * ND + d0 + col];
    lt[(col + 0) * 72 + row] = f2bf(v.x);
    lt[(col + 1) * 72 + row] = f2bf(v.y);
    lt[(col + 2) * 72 + row] = f2bf(v.z);
    lt[(col + 3) * 72 + row] = f2bf(v.w);
  }
  __syncthreads();
  int dl = t >> 2, sc = (t & 3) * 16;
  u16x8 a = *(u16x8*)&lt[dl * 72 + sc];
  u16x8 bb = *(u16x8*)&lt[dl * 72 + sc + 8];
  size_t o = ((size_t)b * ND + d0 + dl) * NS + s0 + sc;
  *(u16x8*)&xt[o] = a;
  *(u16x8*)&xt[o + 8] = bb;
}

// ---------------- m97-style MFMA GEMM: C[b][M][N] = A[M][K] * B[b][N][K]^T ----
// bf16 in, fp32 accum, bf16 out. 256 thr = 4 waves (2x2). BK=64, 16x16x32 MFMA.
// Staging via global_load_lds dwordx4, linear LDS, 2 barriers/K-step (m97: 874 TF class).
// OUTT=0: C[b][M][N] scalar bf16; OUTT=1: C^T[b][N][M] with u16x4 vector stores.
template <int BM, int BN, int OUTT>
__global__ __launch_bounds__(256) void gemm97(const unsigned short* __restrict__ A,
                                              const unsigned short* __restrict__ B,
                                              unsigned short* __restrict__ C,
                                              int M, int N, int K,
                                              size_t sA, size_t sB) {
  constexpr int MI = BM / 32, NI = BN / 32;
  const int mt = M / BM, nt = N / BN;
  int bid = blockIdx.x;
  int b = bid / (mt * nt), r = bid % (mt * nt);
  int m0 = (r / nt) * BM, n0 = (r % nt) * BN;
  int t = threadIdx.x, lane = t & 63, w = t >> 6;
  int wr = (t >> 7) & 1, wc = (t >> 6) & 1;
  __shared__ __attribute__((aligned(16))) unsigned short As[BM * 64];
  __shared__ __attribute__((aligned(16))) unsigned short Bs[BN * 64];
  const unsigned short* Ag = A + b * sA + (size_t)m0 * K;
  const unsigned short* Bg = B + b * sB + (size_t)n0 * K;
  int arow = lane >> 3, ak = (lane & 7) * 8;

  f32x4 acc[MI][NI];
#pragma unroll
  for (int i = 0; i < MI; i++)
#pragma unroll
    for (int j = 0; j < NI; j++) acc[i][j] = {0.f, 0.f, 0.f, 0.f};

  for (int kt = 0; kt < K / 64; kt++) {
    int kofs = kt * 64;
#pragma unroll
    for (int i = 0; i < BM / 32; i++) {  // A: 8 rows per instr per wave
      int r0 = w * (BM / 4) + i * 8;
      gll16(Ag + (size_t)(r0 + arow) * K + kofs + ak, &As[r0 * 64]);
    }
#pragma unroll
    for (int i = 0; i < BN / 32; i++) {
      int r0 = w * (BN / 4) + i * 8;
      gll16(Bg + (size_t)(r0 + arow) * K + kofs + ak, &Bs[r0 * 64]);
    }
    __syncthreads();  // compiler drains vmcnt(0) before barrier
#pragma unroll
    for (int ks = 0; ks < 2; ks++) {
      short8 af[MI], bfv[NI];
#pragma unroll
      for (int mi = 0; mi < MI; mi++) {
        int row = wr * (BM / 2) + mi * 16 + (lane & 15);
        af[mi] = *(const short8*)&As[row * 64 + (ks * 4 + (lane >> 4)) * 8];
      }
#pragma unroll
      for (int ni = 0; ni < NI; ni++) {
        int row = wc * (BN / 2) + ni * 16 + (lane & 15);
        bfv[ni] = *(const short8*)&Bs[row * 64 + (ks * 4 + (lane >> 4)) * 8];
      }
#pragma unroll
      for (int mi = 0; mi < MI; mi++)
#pragma unroll
        for (int ni = 0; ni < NI; ni++)
          acc[mi][ni] = __builtin_amdgcn_mfma_f32_16x16x32_bf16(
              af[mi], bfv[ni], acc[mi][ni], 0, 0, 0);
    }
    __syncthreads();
  }

  // C/D layout: col=lane&15, row=(lane>>4)*4+q  [m89-verified]
#pragma unroll
  for (int mi = 0; mi < MI; mi++) {
#pragma unroll
    for (int ni = 0; ni < NI; ni++) {
      int row0 = m0 + wr * (BM / 2) + mi * 16 + ((lane >> 4) * 4);
      int col = n0 + wc * (BN / 2) + ni * 16 + (lane & 15);
      if (OUTT == 1) {  // C^T: 4 consecutive M-elems -> one u16x4 store
        u16x4 v = {f2bf(acc[mi][ni][0]), f2bf(acc[mi][ni][1]),
                   f2bf(acc[mi][ni][2]), f2bf(acc[mi][ni][3])};
        *(u16x4*)&C[((size_t)b * N + col) * M + row0] = v;
      } else {
#pragma unroll
        for (int q = 0; q < 4; q++)
          C[((size_t)b * M + row0 + q) * N + col] = f2bf(acc[mi][ni][q]);
      }
    }
  }
}

// ---------------- k1bT: RXwT[b][d][k] = mcT*re - msT*im ----------------
__global__ __launch_bounds__(256) void k1bT(const unsigned short* __restrict__ XqT,
                                            const float* __restrict__ mcT,
                                            const float* __restrict__ msT,
                                            unsigned short* __restrict__ RXwT) {
  int gid = blockIdx.x * 256 + threadIdx.x;  // 1024 blocks
  int rw = gid >> 5;                          // b*1024 + d
  int k0 = (gid & 31) * 8;
  int d = rw & 1023;
  u16x8 re = *(const u16x8*)&XqT[(size_t)rw * 512 + k0];
  u16x8 im = *(const u16x8*)&XqT[(size_t)rw * 512 + 256 + k0];
  float4 c0 = *(const float4*)&mcT[d * 256 + k0];
  float4 c1 = *(const float4*)&mcT[d * 256 + k0 + 4];
  float4 s0 = *(const float4*)&msT[d * 256 + k0];
  float4 s1 = *(const float4*)&msT[d * 256 + k0 + 4];
  float cc[8] = {c0.x, c0.y, c0.z, c0.w, c1.x, c1.y, c1.z, c1.w};
  float ss[8] = {s0.x, s0.y, s0.z, s0.w, s1.x, s1.y, s1.z, s1.w};
  u16x8 o;
#pragma unroll
  for (int q = 0; q < 8; q++)
    o[q] = f2bf(cc[q] * bf2f(re[q]) - ss[q] * bf2f(im[q]));
  *(u16x8*)&RXwT[(size_t)rw * 256 + k0] = o;
}

// ---------------- k2b: deltas (transposed domain, coalesced) ----------------
// dre = a*((mcT-1)*re - msT*im + 0.1*I); dim = a*(msT*re + (mcT-1)*im); a=(j==0?1:2)/2048
__global__ __launch_bounds__(256) void k2b(const unsigned short* __restrict__ IT,
                                           const unsigned short* __restrict__ XqT,
                                           const float* __restrict__ mcT,
                                           const float* __restrict__ msT,
                                           unsigned short* __restrict__ DltT) {
  int gid = blockIdx.x * 256 + threadIdx.x;  // 1024 blocks
  int rw = gid >> 5;                          // b*1024 + d
  int j0 = (gid & 31) * 8;
  int d = rw & 1023;
  u16x8 iv = *(const u16x8*)&IT[(size_t)rw * 256 + j0];
  u16x8 re = *(const u16x8*)&XqT[(size_t)rw * 512 + j0];
  u16x8 im = *(const u16x8*)&XqT[(size_t)rw * 512 + 256 + j0];
  float4 c0 = *(const float4*)&mcT[d * 256 + j0];
  float4 c1 = *(const float4*)&mcT[d * 256 + j0 + 4];
  float4 s0 = *(const float4*)&msT[d * 256 + j0];
  float4 s1 = *(const float4*)&msT[d * 256 + j0 + 4];
  float cc[8] = {c0.x, c0.y, c0.z, c0.w, c1.x, c1.y, c1.z, c1.w};
  float ss[8] = {s0.x, s0.y, s0.z, s0.w, s1.x, s1.y, s1.z, s1.w};
  u16x8 orv, oiv;
#pragma unroll
  for (int q = 0; q < 8; q++) {
    int j = j0 + q;
    float alpha = ((j == 0) ? 1.0f : 2.0f) * (1.0f / 2048.0f);
    float xr = bf2f(re[q]), xi = bf2f(im[q]), ii = bf2f(iv[q]);
    float m1 = cc[q] - 1.0f;
    orv[q] = f2bf(alpha * (m1 * xr - ss[q] * xi + 0.1f * ii));
    oiv[q] = f2bf(alpha * (ss[q] * xr + m1 * xi));
  }
  *(u16x8*)&DltT[(size_t)rw * 512 + j0] = orv;
  *(u16x8*)&DltT[(size_t)rw * 512 + 256 + j0] = oiv;
}

// ---------------- K4: y = 2x + corr(bf16), LayerNorm over D ----------------
__global__ __launch_bounds__(256) void k4_ln(const float* __restrict__ x,
                                             const unsigned short* __restrict__ corr,
                                             const float* __restrict__ g,
                                             const float* __restrict__ be,
                                             float* __restrict__ out) {
  int row = blockIdx.x;
  int t = threadIdx.x;
  size_t base = (size_t)row * ND + t * 4;
  u16x4 cv = *(const u16x4*)&corr[base];
  float4 xv = *(const float4*)&x[base];
  float v[4] = {fmaf(2.f, xv.x, bf2f(cv[0])), fmaf(2.f, xv.y, bf2f(cv[1])),
                fmaf(2.f, xv.z, bf2f(cv[2])), fmaf(2.f, xv.w, bf2f(cv[3]))};
  float s = v[0] + v[1] + v[2] + v[3];
  float q = v[0] * v[0] + v[1] * v[1] + v[2] * v[2] + v[3] * v[3];
#pragma unroll
  for (int o = 32; o >= 1; o >>= 1) {
    s += __shfl_xor(s, o, 64);
    q += __shfl_xor(q, o, 64);
  }
  __shared__ float ss[4], qs[4];
  if ((t & 63) == 0) { ss[t >> 6] = s; qs[t >> 6] = q; }
  __syncthreads();
  s = ss[0] + ss[1] + ss[2] + ss[3];
  q = qs[0] + qs[1] + qs[2] + qs[3];
  float mu = s * (1.0f / (float)ND);
  float var = q * (1.0f / (float)ND) - mu * mu;
  float rstd = rsqrtf(var + 1e-5f);
  float4 gv = *(const float4*)&g[t * 4];
  float4 bv = *(const float4*)&be[t * 4];
  float4 ov;
  ov.x = (v[0] - mu) * rstd * gv.x + bv.x;
  ov.y = (v[1] - mu) * rstd * gv.y + bv.y;
  ov.z = (v[2] - mu) * rstd * gv.z + bv.z;
  ov.w = (v[3] - mu) * rstd * gv.w + bv.w;
  *(float4*)&out[base] = ov;
}

extern "C" void kernel_launch(void* const* d_in, const int* in_sizes, int n_in,
                              void* d_out, int out_size, void* d_ws, size_t ws_size,
                              hipStream_t stream) {
  const float* x   = (const float*)d_in[0];
  const float* mag = (const float*)d_in[1];
  const float* ph  = (const float*)d_in[2];
  const float* W   = (const float*)d_in[3];
  const float* g   = (const float*)d_in[4];
  const float* be  = (const float*)d_in[5];
  float* out = (float*)d_out;
  char* w = (char*)d_ws;

  // ws layout (MB offsets), ~95 MB total (ws is 256 MB per fill counters):
  unsigned short* CF   = (unsigned short*)(w);                    // 2 MB
  unsigned short* CS   = (unsigned short*)(w + (2ull << 20));     // 2 MB
  float*          mcT  = (float*)(w + (4ull << 20));              // 1 MB [d][k]
  float*          msT  = (float*)(w + (5ull << 20));              // 1 MB
  unsigned short* WT   = (unsigned short*)(w + (6ull << 20));     // 128 KB [j][k]
  unsigned short* XqT  = (unsigned short*)(w + (7ull << 20));     // 8 MB [b][d][512]
  unsigned short* RXwT = (unsigned short*)(w + (15ull << 20));    // 4 MB [b][d][256]
  unsigned short* IT   = (unsigned short*)(w + (19ull << 20));    // 4 MB [b][d][256]
  unsigned short* DltT = (unsigned short*)(w + (23ull << 20));    // 8 MB [b][d][512]
  unsigned short* corr = (unsigned short*)(w + (31ull << 20));    // 32 MB [b][s][d]
  unsigned short* xt   = (unsigned short*)(w + (63ull << 20));    // 32 MB [b][d][s]

  k_tab<<<8192, 256, 0, stream>>>(CF, CS);
  k_cwT<<<64, 256, 0, stream>>>(mag, ph, mcT, msT);
  k_wt<<<16, 256, 0, stream>>>(W, WT);
  k_conv<<<4096, 256, 0, stream>>>(x, xt);
  // Xq^T[b][d][m] = sum_s CF[m][s] * x[b][s][d]
  gemm97<128, 64, 1><<<512, 256, 0, stream>>>(CF, xt, XqT, 512, 1024, 2048,
                                              0, (size_t)1024 * 2048);
  k1bT<<<1024, 256, 0, stream>>>(XqT, mcT, msT, RXwT);
  // I^T[b][d][j] = sum_k RXwT[b][d][k] * WT[j][k]
  gemm97<128, 64, 0><<<256, 256, 0, stream>>>(RXwT, WT, IT, 1024, 256, 256,
                                              (size_t)1024 * 256, 0);
  k2b<<<1024, 256, 0, stream>>>(IT, XqT, mcT, msT, DltT);
  // corr[b][s][d] = sum_m CS[s][m] * DltT[b][d][m]
  gemm97<128, 128, 0><<<1024, 256, 0, stream>>>(CS, DltT, corr, 2048, 1024, 512,
                                                0, (size_t)1024 * 512);
  k4_ln<<<16384, 256, 0, stream>>>(x, corr, g, be, out);
}

// Round 5
// 236.579 us; speedup vs baseline: 3.7111x; 1.0121x over previous
//
#include <hip/hip_runtime.h>
#include <math.h>

#define NS 2048
#define ND 1024
#define NK 256
#define NB 8

typedef __attribute__((ext_vector_type(8))) short short8;
typedef __attribute__((ext_vector_type(4))) float f32x4;
typedef __attribute__((ext_vector_type(4))) unsigned short u16x4;
typedef __attribute__((ext_vector_type(8))) unsigned short u16x8;
typedef unsigned int u32;

__device__ __forceinline__ unsigned short f2bf(float x) {
  unsigned int u = __float_as_uint(x);
  u = (u + 0x7fffu + ((u >> 16) & 1u)) >> 16;
  return (unsigned short)u;
}
__device__ __forceinline__ float bf2f(unsigned short h) {
  return __uint_as_float(((unsigned int)h) << 16);
}

__device__ __forceinline__ int fpos(int k) {
  // np.linspace(0, 512, 256).astype(int64); fp32 floor safe except endpoints.
  return (k == 255) ? 512 : (int)((float)k * (512.0f / 255.0f));
}

// async global->LDS, 16B/lane; LDS dest wave-uniform base + lane*16.
__device__ __forceinline__ void gll16(const unsigned short* g, unsigned short* l) {
  __builtin_amdgcn_global_load_lds(
      (__attribute__((address_space(1))) void*)(void*)const_cast<unsigned short*>(g),
      (__attribute__((address_space(3))) void*)l, 16, 0, 0);
}

// ---------------- master cos table: master[t] = cos(2pi t/2048) ----------------
__global__ __launch_bounds__(256) void k_master(float* __restrict__ master) {
  int t = blockIdx.x * 256 + threadIdx.x;  // 8 blocks
  double th = (double)t * (6.283185307179586476925286766559 / 2048.0);
  master[t] = (float)cos(th);
}

// ---------------- trig tables, interleaved (re,im) layout ----------------
// CFi [512][2048]: row 2j = cos(2pi f_j s/2048), row 2j+1 = -sin(...)
// CSi [2048][512]: col 2j = cos, col 2j+1 = -sin
__global__ __launch_bounds__(256) void k_tabs(const float* __restrict__ master,
                                              unsigned short* __restrict__ CFi,
                                              unsigned short* __restrict__ CSi) {
  int gid = blockIdx.x * 256 + threadIdx.x;  // 8192 blocks
  if (gid < 512 * 2048) {
    int r = gid >> 11, s = gid & 2047;
    int p = (fpos(r >> 1) * s) & 2047;
    float v = (r & 1) ? -master[(p + 1536) & 2047] : master[p];
    CFi[gid] = f2bf(v);
  } else {
    int g = gid - 512 * 2048;
    int s = g >> 9, c = g & 511;
    int p = (fpos(c >> 1) * s) & 2047;
    float v = (c & 1) ? -master[(p + 1536) & 2047] : master[p];
    CSi[g] = f2bf(v);
  }
}

// ---------------- k_cw2: mc/ms in [k][d] AND transposed [d][k] (fp32) ----------------
__global__ __launch_bounds__(256) void k_cw2(const float* __restrict__ mag,
                                             const float* __restrict__ ph,
                                             float* __restrict__ mc,
                                             float* __restrict__ ms,
                                             float* __restrict__ mcT,
                                             float* __restrict__ msT) {
  int bid = blockIdx.x;  // 64 = 4 ktile x 16 dtile, each 64k x 64d
  int kt = bid >> 4, dt = bid & 15;
  int t = threadIdx.x;
  __shared__ float lc[64][68], ls[64][68];
  int kl = t >> 4, d4 = (t & 15) * 4;
#pragma unroll
  for (int i = 0; i < 4; i++) {
    int k = i * 16 + kl;
    size_t off = (size_t)(kt * 64 + k) * ND + dt * 64 + d4;
    float4 mg = *(const float4*)&mag[off];
    float4 pp = *(const float4*)&ph[off];
    float m[4] = {mg.x, mg.y, mg.z, mg.w}, p[4] = {pp.x, pp.y, pp.z, pp.w};
    float4 vc, vs;
    float oc[4], os[4];
#pragma unroll
    for (int q = 0; q < 4; q++) {
      float sp, cp;
      sincosf(p[q], &sp, &cp);
      oc[q] = m[q] * cp;
      os[q] = m[q] * sp;
      lc[k][d4 + q] = oc[q];
      ls[k][d4 + q] = os[q];
    }
    vc = make_float4(oc[0], oc[1], oc[2], oc[3]);
    vs = make_float4(os[0], os[1], os[2], os[3]);
    *(float4*)&mc[off] = vc;
    *(float4*)&ms[off] = vs;
  }
  __syncthreads();
  int dl = t >> 2, kc = (t & 3) * 16;
#pragma unroll
  for (int i = 0; i < 16; i += 4) {
    float4 vc = {lc[kc + i][dl], lc[kc + i + 1][dl], lc[kc + i + 2][dl], lc[kc + i + 3][dl]};
    float4 vs = {ls[kc + i][dl], ls[kc + i + 1][dl], ls[kc + i + 2][dl], ls[kc + i + 3][dl]};
    size_t o = (size_t)(dt * 64 + dl) * 256 + kt * 64 + kc + i;
    *(float4*)&mcT[o] = vc;
    *(float4*)&msT[o] = vs;
  }
}

// ---------------- k_wt: WT[j][k] bf16 = W[k][j] ----------------
__global__ __launch_bounds__(256) void k_wt(const float* __restrict__ W,
                                            unsigned short* __restrict__ WT) {
  int bid = blockIdx.x;  // 16 = 4 kt x 4 jt
  int kt = bid >> 2, jt = bid & 3;
  int t = threadIdx.x;
  __shared__ float lw[64][68];
  int kl = t >> 4, j4 = (t & 15) * 4;
#pragma unroll
  for (int i = 0; i < 4; i++) {
    int k = i * 16 + kl;
    float4 wv = *(const float4*)&W[(size_t)(kt * 64 + k) * 256 + jt * 64 + j4];
    lw[k][j4 + 0] = wv.x; lw[k][j4 + 1] = wv.y;
    lw[k][j4 + 2] = wv.z; lw[k][j4 + 3] = wv.w;
  }
  __syncthreads();
  int jl = t >> 2, kc = (t & 3) * 16;
#pragma unroll
  for (int i = 0; i < 16; i += 4) {
    u16x4 v = {f2bf(lw[kc + i][jl]), f2bf(lw[kc + i + 1][jl]),
               f2bf(lw[kc + i + 2][jl]), f2bf(lw[kc + i + 3][jl])};
    *(u16x4*)&WT[(size_t)(jt * 64 + jl) * 256 + kt * 64 + kc + i] = v;
  }
}

// ---------------- conv: x fp32 [b][s][d] -> xt bf16 [b][d][s] ----------------
__global__ __launch_bounds__(256) void k_conv(const float* __restrict__ x,
                                              unsigned short* __restrict__ xt) {
  int bid = blockIdx.x;  // 8b * 32st * 16dt = 4096
  int b = bid >> 9, rem = bid & 511;
  int s0 = (rem >> 4) * 64, d0 = (rem & 15) * 64;
  int t = threadIdx.x;
  __shared__ __attribute__((aligned(16))) unsigned short lt[64 * 72];  // [d][s+pad]
#pragma unroll
  for (int c = 0; c < 4; c++) {
    int e = c * 256 + t;
    int row = e >> 4, col = (e & 15) * 4;
    float4 v = *(const float4*)&x[((size_t)b * NS + s0 + row) * ND + d0 + col];
    lt[(col + 0) * 72 + row] = f2bf(v.x);
    lt[(col + 1) * 72 + row] = f2bf(v.y);
    lt[(col + 2) * 72 + row] = f2bf(v.z);
    lt[(col + 3) * 72 + row] = f2bf(v.w);
  }
  __syncthreads();
  int dl = t >> 2, sc = (t & 3) * 16;
  u16x8 a = *(u16x8*)&lt[dl * 72 + sc];
  u16x8 bb = *(u16x8*)&lt[dl * 72 + sc + 8];
  size_t o = ((size_t)b * ND + d0 + dl) * NS + s0 + sc;
  *(u16x8*)&xt[o] = a;
  *(u16x8*)&xt[o + 8] = bb;
}

// ---------------- double-buffered MFMA GEMM: C[b][M][N] = A[M][K]*B[b][N][K]^T ----
// 256 thr = 4 waves (2x2). BK=64, 16x16x32 bf16 MFMA, fp32 accum.
// Depth-2 prefetch via global_load_lds + counted vmcnt + raw s_barrier (T3/T4-lite).
// EPI 0: C0[b][M][N] bf16.
// EPI 1 (forward DFT, interleaved re/im rows): C0=XqT[b][N][M], C1=RXwT[b][N][M/2],
//        P0=mc[k][d], P1=ms[k][d].
// EPI 2 (interference): C0=DltT[b][M][512], C1=XqT (read), P0=mcT[d][k], P1=msT[d][k].
template <int BM, int BN, int EPI>
__global__ __launch_bounds__(256) void gemm_db(const unsigned short* __restrict__ A,
                                               const unsigned short* __restrict__ B,
                                               unsigned short* __restrict__ C0,
                                               unsigned short* __restrict__ C1,
                                               const float* __restrict__ P0,
                                               const float* __restrict__ P1,
                                               int M, int N, int K,
                                               size_t sA, size_t sB) {
  constexpr int MI = BM / 32, NI = BN / 32;
  constexpr int NSTG = (BM + BN) / 32;  // gll16 instrs per stage
  const int mt = M / BM, nt = N / BN;
  int bid = blockIdx.x;
  int b = bid / (mt * nt), r = bid % (mt * nt);
  int m0 = (r / nt) * BM, n0 = (r % nt) * BN;
  int t = threadIdx.x, lane = t & 63, w = t >> 6;
  int wr = (t >> 7) & 1, wc = (t >> 6) & 1;
  __shared__ __attribute__((aligned(16))) unsigned short As[2][BM * 64];
  __shared__ __attribute__((aligned(16))) unsigned short Bs[2][BN * 64];
  const unsigned short* Ag = A + b * sA + (size_t)m0 * K;
  const unsigned short* Bg = B + b * sB + (size_t)n0 * K;
  int arow = lane >> 3, ak = (lane & 7) * 8;

  f32x4 acc[MI][NI];
#pragma unroll
  for (int i = 0; i < MI; i++)
#pragma unroll
    for (int j = 0; j < NI; j++) acc[i][j] = {0.f, 0.f, 0.f, 0.f};

  const int nkt = K / 64;

#define STAGE(buf, kt_)                                                      \
  do {                                                                       \
    int kofs = (kt_) * 64;                                                   \
    _Pragma("unroll") for (int i = 0; i < BM / 32; i++) {                    \
      int r0 = w * (BM / 4) + i * 8;                                         \
      gll16(Ag + (size_t)(r0 + arow) * K + kofs + ak, &As[buf][r0 * 64]);    \
    }                                                                        \
    _Pragma("unroll") for (int i = 0; i < BN / 32; i++) {                    \
      int r0 = w * (BN / 4) + i * 8;                                         \
      gll16(Bg + (size_t)(r0 + arow) * K + kofs + ak, &Bs[buf][r0 * 64]);    \
    }                                                                        \
  } while (0)

  STAGE(0, 0);
  if (nkt > 1) STAGE(1, 1);

  for (int kt = 0; kt < nkt; kt++) {
    int cur = kt & 1;
    if (kt + 1 < nkt)
      asm volatile("s_waitcnt vmcnt(%0)" ::"n"(NSTG) : "memory");
    else
      asm volatile("s_waitcnt vmcnt(0)" ::: "memory");
    __builtin_amdgcn_s_barrier();
#pragma unroll
    for (int ks = 0; ks < 2; ks++) {
      short8 af[MI], bfv[NI];
#pragma unroll
      for (int mi = 0; mi < MI; mi++) {
        int row = wr * (BM / 2) + mi * 16 + (lane & 15);
        af[mi] = *(const short8*)&As[cur][row * 64 + (ks * 4 + (lane >> 4)) * 8];
      }
#pragma unroll
      for (int ni = 0; ni < NI; ni++) {
        int row = wc * (BN / 2) + ni * 16 + (lane & 15);
        bfv[ni] = *(const short8*)&Bs[cur][row * 64 + (ks * 4 + (lane >> 4)) * 8];
      }
#pragma unroll
      for (int mi = 0; mi < MI; mi++)
#pragma unroll
        for (int ni = 0; ni < NI; ni++)
          acc[mi][ni] = __builtin_amdgcn_mfma_f32_16x16x32_bf16(
              af[mi], bfv[ni], acc[mi][ni], 0, 0, 0);
    }
    __builtin_amdgcn_s_barrier();  // all waves done reading buf cur
    if (kt + 2 < nkt) STAGE(cur, kt + 2);
  }
#undef STAGE

  // C/D layout: col=lane&15, row=(lane>>4)*4+q  [m89-verified]
#pragma unroll
  for (int mi = 0; mi < MI; mi++) {
#pragma unroll
    for (int ni = 0; ni < NI; ni++) {
      int row0 = m0 + wr * (BM / 2) + mi * 16 + ((lane >> 4) * 4);
      int col = n0 + wc * (BN / 2) + ni * 16 + (lane & 15);
      f32x4 a = acc[mi][ni];
      if (EPI == 0) {
#pragma unroll
        for (int q = 0; q < 4; q++)
          C0[((size_t)b * M + row0 + q) * N + col] = f2bf(a[q]);
      } else if (EPI == 1) {
        // rows row0..row0+3 = bins j0 (re,im), j0+1 (re,im)
        u16x4 xv = {f2bf(a[0]), f2bf(a[1]), f2bf(a[2]), f2bf(a[3])};
        *(u16x4*)&C0[((size_t)b * N + col) * M + row0] = xv;
        int j0 = row0 >> 1, j1 = j0 + 1;
        float rw0 = P0[(size_t)j0 * ND + col] * a[0] - P1[(size_t)j0 * ND + col] * a[1];
        float rw1 = P0[(size_t)j1 * ND + col] * a[2] - P1[(size_t)j1 * ND + col] * a[3];
        u32 pk = (u32)f2bf(rw0) | ((u32)f2bf(rw1) << 16);
        *(u32*)&C1[((size_t)b * N + col) * (M / 2) + j0] = pk;
      } else {
        // EPI 2: rows=d, cols=j. DltT[b][d][2j]=dre, [2j+1]=dim
        float alpha = ((col == 0) ? 1.0f : 2.0f) * (1.0f / 2048.0f);
#pragma unroll
        for (int q = 0; q < 4; q++) {
          int dd = row0 + q;
          u32 reim = *(const u32*)&C1[((size_t)b * M + dd) * 512 + 2 * col];
          float xr = bf2f((unsigned short)(reim & 0xffffu));
          float xi = bf2f((unsigned short)(reim >> 16));
          float mcv = P0[(size_t)dd * 256 + col];
          float msv = P1[(size_t)dd * 256 + col];
          float m1 = mcv - 1.0f;
          float dre = alpha * (m1 * xr - msv * xi + 0.1f * a[q]);
          float dim = alpha * (msv * xr + m1 * xi);
          u32 pk = (u32)f2bf(dre) | ((u32)f2bf(dim) << 16);
          *(u32*)&C0[((size_t)b * M + dd) * 512 + 2 * col] = pk;
        }
      }
    }
  }
}

// ---------------- K4: y = 2x + corr(bf16), LayerNorm over D ----------------
__global__ __launch_bounds__(256) void k4_ln(const float* __restrict__ x,
                                             const unsigned short* __restrict__ corr,
                                             const float* __restrict__ g,
                                             const float* __restrict__ be,
                                             float* __restrict__ out) {
  int row = blockIdx.x;
  int t = threadIdx.x;
  size_t base = (size_t)row * ND + t * 4;
  u16x4 cv = *(const u16x4*)&corr[base];
  float4 xv = *(const float4*)&x[base];
  float v[4] = {fmaf(2.f, xv.x, bf2f(cv[0])), fmaf(2.f, xv.y, bf2f(cv[1])),
                fmaf(2.f, xv.z, bf2f(cv[2])), fmaf(2.f, xv.w, bf2f(cv[3]))};
  float s = v[0] + v[1] + v[2] + v[3];
  float q = v[0] * v[0] + v[1] * v[1] + v[2] * v[2] + v[3] * v[3];
#pragma unroll
  for (int o = 32; o >= 1; o >>= 1) {
    s += __shfl_xor(s, o, 64);
    q += __shfl_xor(q, o, 64);
  }
  __shared__ float ss[4], qs[4];
  if ((t & 63) == 0) { ss[t >> 6] = s; qs[t >> 6] = q; }
  __syncthreads();
  s = ss[0] + ss[1] + ss[2] + ss[3];
  q = qs[0] + qs[1] + qs[2] + qs[3];
  float mu = s * (1.0f / (float)ND);
  float var = q * (1.0f / (float)ND) - mu * mu;
  float rstd = rsqrtf(var + 1e-5f);
  float4 gv = *(const float4*)&g[t * 4];
  float4 bv = *(const float4*)&be[t * 4];
  float4 ov;
  ov.x = (v[0] - mu) * rstd * gv.x + bv.x;
  ov.y = (v[1] - mu) * rstd * gv.y + bv.y;
  ov.z = (v[2] - mu) * rstd * gv.z + bv.z;
  ov.w = (v[3] - mu) * rstd * gv.w + bv.w;
  *(float4*)&out[base] = ov;
}

extern "C" void kernel_launch(void* const* d_in, const int* in_sizes, int n_in,
                              void* d_out, int out_size, void* d_ws, size_t ws_size,
                              hipStream_t stream) {
  const float* x   = (const float*)d_in[0];
  const float* mag = (const float*)d_in[1];
  const float* ph  = (const float*)d_in[2];
  const float* W   = (const float*)d_in[3];
  const float* g   = (const float*)d_in[4];
  const float* be  = (const float*)d_in[5];
  float* out = (float*)d_out;
  char* w = (char*)d_ws;

  float*          master = (float*)(w);                          // 8 KB
  unsigned short* CFi    = (unsigned short*)(w + (1ull << 20));  // 2 MB [512][2048]
  unsigned short* CSi    = (unsigned short*)(w + (3ull << 20));  // 2 MB [2048][512]
  float*          mc     = (float*)(w + (5ull << 20));           // 1 MB [k][d]
  float*          ms     = (float*)(w + (6ull << 20));           // 1 MB
  float*          mcT    = (float*)(w + (7ull << 20));           // 1 MB [d][k]
  float*          msT    = (float*)(w + (8ull << 20));           // 1 MB
  unsigned short* WT     = (unsigned short*)(w + (9ull << 20));  // 128 KB [j][k]
  unsigned short* XqT    = (unsigned short*)(w + (10ull << 20)); // 8 MB [b][d][512] ilv
  unsigned short* RXwT   = (unsigned short*)(w + (18ull << 20)); // 4 MB [b][d][256]
  unsigned short* DltT   = (unsigned short*)(w + (22ull << 20)); // 8 MB [b][d][512] ilv
  unsigned short* corr   = (unsigned short*)(w + (30ull << 20)); // 32 MB [b][s][d]
  unsigned short* xt     = (unsigned short*)(w + (62ull << 20)); // 32 MB [b][d][s]

  k_master<<<8, 256, 0, stream>>>(master);
  k_tabs<<<8192, 256, 0, stream>>>(master, CFi, CSi);
  k_cw2<<<64, 256, 0, stream>>>(mag, ph, mc, ms, mcT, msT);
  k_wt<<<16, 256, 0, stream>>>(W, WT);
  k_conv<<<4096, 256, 0, stream>>>(x, xt);
  // forward DFT + ReXw fusion: XqT[b][d][m], RXwT[b][d][k]
  gemm_db<128, 64, 1><<<512, 256, 0, stream>>>(CFi, xt, XqT, RXwT, mc, ms,
                                               512, 1024, 2048, 0,
                                               (size_t)1024 * 2048);
  // interference + delta fusion: DltT[b][d][512]
  gemm_db<128, 64, 2><<<256, 256, 0, stream>>>(RXwT, WT, DltT, XqT, mcT, msT,
                                               1024, 256, 256,
                                               (size_t)1024 * 256, 0);
  // synthesis: corr[b][s][d]
  gemm_db<128, 128, 0><<<1024, 256, 0, stream>>>(CSi, DltT, corr, nullptr,
                                                 nullptr, nullptr,
                                                 2048, 1024, 512, 0,
                                                 (size_t)1024 * 512);
  k4_ln<<<16384, 256, 0, stream>>>(x, corr, g, be, out);
}

// Round 6
// 225.295 us; speedup vs baseline: 3.8969x; 1.0501x over previous
//
#include <hip/hip_runtime.h>
#include <math.h>

#define NS 2048
#define ND 1024
#define NK 256
#define NB 8

typedef __attribute__((ext_vector_type(8))) short short8;
typedef __attribute__((ext_vector_type(4))) float f32x4;
typedef __attribute__((ext_vector_type(4))) unsigned short u16x4;
typedef __attribute__((ext_vector_type(8))) unsigned short u16x8;
typedef unsigned int u32;

__device__ __forceinline__ unsigned short f2bf(float x) {
  unsigned int u = __float_as_uint(x);
  u = (u + 0x7fffu + ((u >> 16) & 1u)) >> 16;
  return (unsigned short)u;
}
__device__ __forceinline__ float bf2f(unsigned short h) {
  return __uint_as_float(((unsigned int)h) << 16);
}

__device__ __forceinline__ int fpos(int k) {
  // np.linspace(0, 512, 256).astype(int64); fp32 floor safe except endpoints.
  return (k == 255) ? 512 : (int)((float)k * (512.0f / 255.0f));
}

// async global->LDS, 16B/lane; LDS dest wave-uniform base + lane*16.
__device__ __forceinline__ void gll16(const unsigned short* g, unsigned short* l) {
  __builtin_amdgcn_global_load_lds(
      (__attribute__((address_space(1))) void*)(void*)const_cast<unsigned short*>(g),
      (__attribute__((address_space(3))) void*)l, 16, 0, 0);
}

// ---------------- master cos table: master[t] = cos(2pi t/2048) ----------------
__global__ __launch_bounds__(256) void k_master(float* __restrict__ master) {
  int t = blockIdx.x * 256 + threadIdx.x;  // 8 blocks
  double th = (double)t * (6.283185307179586476925286766559 / 2048.0);
  master[t] = (float)cos(th);
}

// ---------------- trig tables, interleaved (re,im) layout ----------------
// CFi [512][2048]: row 2j = cos(2pi f_j s/2048), row 2j+1 = -sin(...)
// CSi [2048][512]: col 2j = cos, col 2j+1 = -sin
__global__ __launch_bounds__(256) void k_tabs(const float* __restrict__ master,
                                              unsigned short* __restrict__ CFi,
                                              unsigned short* __restrict__ CSi) {
  int gid = blockIdx.x * 256 + threadIdx.x;  // 8192 blocks
  if (gid < 512 * 2048) {
    int r = gid >> 11, s = gid & 2047;
    int p = (fpos(r >> 1) * s) & 2047;
    float v = (r & 1) ? -master[(p + 1536) & 2047] : master[p];
    CFi[gid] = f2bf(v);
  } else {
    int g = gid - 512 * 2048;
    int s = g >> 9, c = g & 511;
    int p = (fpos(c >> 1) * s) & 2047;
    float v = (c & 1) ? -master[(p + 1536) & 2047] : master[p];
    CSi[g] = f2bf(v);
  }
}

// ---------------- k_cw2: mc/ms in [k][d] AND transposed [d][k] (fp32) ----------------
__global__ __launch_bounds__(256) void k_cw2(const float* __restrict__ mag,
                                             const float* __restrict__ ph,
                                             float* __restrict__ mc,
                                             float* __restrict__ ms,
                                             float* __restrict__ mcT,
                                             float* __restrict__ msT) {
  int bid = blockIdx.x;  // 64 = 4 ktile x 16 dtile, each 64k x 64d
  int kt = bid >> 4, dt = bid & 15;
  int t = threadIdx.x;
  __shared__ float lc[64][68], ls[64][68];
  int kl = t >> 4, d4 = (t & 15) * 4;
#pragma unroll
  for (int i = 0; i < 4; i++) {
    int k = i * 16 + kl;
    size_t off = (size_t)(kt * 64 + k) * ND + dt * 64 + d4;
    float4 mg = *(const float4*)&mag[off];
    float4 pp = *(const float4*)&ph[off];
    float m[4] = {mg.x, mg.y, mg.z, mg.w}, p[4] = {pp.x, pp.y, pp.z, pp.w};
    float oc[4], os[4];
#pragma unroll
    for (int q = 0; q < 4; q++) {
      float sp, cp;
      sincosf(p[q], &sp, &cp);
      oc[q] = m[q] * cp;
      os[q] = m[q] * sp;
      lc[k][d4 + q] = oc[q];
      ls[k][d4 + q] = os[q];
    }
    *(float4*)&mc[off] = make_float4(oc[0], oc[1], oc[2], oc[3]);
    *(float4*)&ms[off] = make_float4(os[0], os[1], os[2], os[3]);
  }
  __syncthreads();
  int dl = t >> 2, kc = (t & 3) * 16;
#pragma unroll
  for (int i = 0; i < 16; i += 4) {
    float4 vc = {lc[kc + i][dl], lc[kc + i + 1][dl], lc[kc + i + 2][dl], lc[kc + i + 3][dl]};
    float4 vs = {ls[kc + i][dl], ls[kc + i + 1][dl], ls[kc + i + 2][dl], ls[kc + i + 3][dl]};
    size_t o = (size_t)(dt * 64 + dl) * 256 + kt * 64 + kc + i;
    *(float4*)&mcT[o] = vc;
    *(float4*)&msT[o] = vs;
  }
}

// ---------------- k_wt: WT[j][k] bf16 = W[k][j] ----------------
__global__ __launch_bounds__(256) void k_wt(const float* __restrict__ W,
                                            unsigned short* __restrict__ WT) {
  int bid = blockIdx.x;  // 16 = 4 kt x 4 jt
  int kt = bid >> 2, jt = bid & 3;
  int t = threadIdx.x;
  __shared__ float lw[64][68];
  int kl = t >> 4, j4 = (t & 15) * 4;
#pragma unroll
  for (int i = 0; i < 4; i++) {
    int k = i * 16 + kl;
    float4 wv = *(const float4*)&W[(size_t)(kt * 64 + k) * 256 + jt * 64 + j4];
    lw[k][j4 + 0] = wv.x; lw[k][j4 + 1] = wv.y;
    lw[k][j4 + 2] = wv.z; lw[k][j4 + 3] = wv.w;
  }
  __syncthreads();
  int jl = t >> 2, kc = (t & 3) * 16;
#pragma unroll
  for (int i = 0; i < 16; i += 4) {
    u16x4 v = {f2bf(lw[kc + i][jl]), f2bf(lw[kc + i + 1][jl]),
               f2bf(lw[kc + i + 2][jl]), f2bf(lw[kc + i + 3][jl])};
    *(u16x4*)&WT[(size_t)(jt * 64 + jl) * 256 + kt * 64 + kc + i] = v;
  }
}

// ---------------- conv: x fp32 [b][s][d] -> xt bf16 [b][d][s] ----------------
__global__ __launch_bounds__(256) void k_conv(const float* __restrict__ x,
                                              unsigned short* __restrict__ xt) {
  int bid = blockIdx.x;  // 8b * 32st * 16dt = 4096
  int b = bid >> 9, rem = bid & 511;
  int s0 = (rem >> 4) * 64, d0 = (rem & 15) * 64;
  int t = threadIdx.x;
  __shared__ __attribute__((aligned(16))) unsigned short lt[64 * 72];  // [d][s+pad]
#pragma unroll
  for (int c = 0; c < 4; c++) {
    int e = c * 256 + t;
    int row = e >> 4, col = (e & 15) * 4;
    float4 v = *(const float4*)&x[((size_t)b * NS + s0 + row) * ND + d0 + col];
    lt[(col + 0) * 72 + row] = f2bf(v.x);
    lt[(col + 1) * 72 + row] = f2bf(v.y);
    lt[(col + 2) * 72 + row] = f2bf(v.z);
    lt[(col + 3) * 72 + row] = f2bf(v.w);
  }
  __syncthreads();
  int dl = t >> 2, sc = (t & 3) * 16;
  u16x8 a = *(u16x8*)&lt[dl * 72 + sc];
  u16x8 bb = *(u16x8*)&lt[dl * 72 + sc + 8];
  size_t o = ((size_t)b * ND + d0 + dl) * NS + s0 + sc;
  *(u16x8*)&xt[o] = a;
  *(u16x8*)&xt[o + 8] = bb;
}

// ---------------- double-buffered MFMA GEMM: C[b][M][N] = A[M][K]*B[b][N][K]^T ----
// 256 thr = 4 waves (2x2). BK=64, 16x16x32 bf16 MFMA, fp32 accum.
// Depth-2 prefetch via global_load_lds + counted vmcnt + raw s_barrier (T3/T4-lite).
// T2 both-sides XOR swizzle (rule 21): gll16 writes LDS linearly, lane loads global
// chunk (lane&7)^(lane>>3); ds_read XORs slot with row&7. Kills the 16-way conflict.
// T1 bijective XCD swizzle (grid % 8 == 0).
// EPI 0: C0[b][M][N] bf16.
// EPI 1 (forward DFT): C0=XqT[b][N][M] ilv, C1=RXwT[b][N][M/2], P0=mc[k][d], P1=ms[k][d].
// EPI 2 (interference): C0=DltT[b][M][512] ilv, C1=XqT (read), P0=mcT[d][k], P1=msT[d][k].
template <int BM, int BN, int EPI>
__global__ __launch_bounds__(256) void gemm_db(const unsigned short* __restrict__ A,
                                               const unsigned short* __restrict__ B,
                                               unsigned short* __restrict__ C0,
                                               unsigned short* __restrict__ C1,
                                               const float* __restrict__ P0,
                                               const float* __restrict__ P1,
                                               int M, int N, int K,
                                               size_t sA, size_t sB) {
  constexpr int MI = BM / 32, NI = BN / 32;
  constexpr int NSTG = (BM + BN) / 32;  // gll16 instrs per stage per wave
  const int mt = M / BM, nt = N / BN;
  int nwg = gridDim.x;
  int bid0 = blockIdx.x;
  int bid = (bid0 & 7) * (nwg >> 3) + (bid0 >> 3);  // XCD swizzle (nwg%8==0)
  int b = bid / (mt * nt), r = bid % (mt * nt);
  int m0 = (r / nt) * BM, n0 = (r % nt) * BN;
  int t = threadIdx.x, lane = t & 63, w = t >> 6;
  int wr = (t >> 7) & 1, wc = (t >> 6) & 1;
  __shared__ __attribute__((aligned(16))) unsigned short As[2][BM * 64];
  __shared__ __attribute__((aligned(16))) unsigned short Bs[2][BN * 64];
  const unsigned short* Ag = A + b * sA + (size_t)m0 * K;
  const unsigned short* Bg = B + b * sB + (size_t)n0 * K;
  int arow = lane >> 3;
  int aswz = ((lane & 7) ^ (lane >> 3)) * 8;  // pre-swizzled global k-chunk

  f32x4 acc[MI][NI];
#pragma unroll
  for (int i = 0; i < MI; i++)
#pragma unroll
    for (int j = 0; j < NI; j++) acc[i][j] = {0.f, 0.f, 0.f, 0.f};

  const int nkt = K / 64;

#define STAGE(buf, kt_)                                                       \
  do {                                                                        \
    int kofs = (kt_) * 64;                                                    \
    _Pragma("unroll") for (int i = 0; i < BM / 32; i++) {                     \
      int r0 = w * (BM / 4) + i * 8;                                          \
      gll16(Ag + (size_t)(r0 + arow) * K + kofs + aswz, &As[buf][r0 * 64]);   \
    }                                                                         \
    _Pragma("unroll") for (int i = 0; i < BN / 32; i++) {                     \
      int r0 = w * (BN / 4) + i * 8;                                          \
      gll16(Bg + (size_t)(r0 + arow) * K + kofs + aswz, &Bs[buf][r0 * 64]);   \
    }                                                                         \
  } while (0)

  STAGE(0, 0);
  if (nkt > 1) STAGE(1, 1);

  for (int kt = 0; kt < nkt; kt++) {
    int cur = kt & 1;
    if (kt + 1 < nkt)
      asm volatile("s_waitcnt vmcnt(%0)" ::"n"(NSTG) : "memory");
    else
      asm volatile("s_waitcnt vmcnt(0)" ::: "memory");
    __builtin_amdgcn_s_barrier();
#pragma unroll
    for (int ks = 0; ks < 2; ks++) {
      short8 af[MI], bfv[NI];
#pragma unroll
      for (int mi = 0; mi < MI; mi++) {
        int row = wr * (BM / 2) + mi * 16 + (lane & 15);
        int sl = (ks * 4 + (lane >> 4)) ^ (row & 7);
        af[mi] = *(const short8*)&As[cur][row * 64 + sl * 8];
      }
#pragma unroll
      for (int ni = 0; ni < NI; ni++) {
        int row = wc * (BN / 2) + ni * 16 + (lane & 15);
        int sl = (ks * 4 + (lane >> 4)) ^ (row & 7);
        bfv[ni] = *(const short8*)&Bs[cur][row * 64 + sl * 8];
      }
#pragma unroll
      for (int mi = 0; mi < MI; mi++)
#pragma unroll
        for (int ni = 0; ni < NI; ni++)
          acc[mi][ni] = __builtin_amdgcn_mfma_f32_16x16x32_bf16(
              af[mi], bfv[ni], acc[mi][ni], 0, 0, 0);
    }
    __builtin_amdgcn_s_barrier();  // all waves done reading buf cur
    if (kt + 2 < nkt) STAGE(cur, kt + 2);
  }
#undef STAGE

  // C/D layout: col=lane&15, row=(lane>>4)*4+q  [m89-verified]
#pragma unroll
  for (int mi = 0; mi < MI; mi++) {
#pragma unroll
    for (int ni = 0; ni < NI; ni++) {
      int row0 = m0 + wr * (BM / 2) + mi * 16 + ((lane >> 4) * 4);
      int col = n0 + wc * (BN / 2) + ni * 16 + (lane & 15);
      f32x4 a = acc[mi][ni];
      if (EPI == 0) {
#pragma unroll
        for (int q = 0; q < 4; q++)
          C0[((size_t)b * M + row0 + q) * N + col] = f2bf(a[q]);
      } else if (EPI == 1) {
        // rows row0..row0+3 = bins j0 (re,im), j0+1 (re,im)
        u16x4 xv = {f2bf(a[0]), f2bf(a[1]), f2bf(a[2]), f2bf(a[3])};
        *(u16x4*)&C0[((size_t)b * N + col) * M + row0] = xv;
        int j0 = row0 >> 1, j1 = j0 + 1;
        float rw0 = P0[(size_t)j0 * ND + col] * a[0] - P1[(size_t)j0 * ND + col] * a[1];
        float rw1 = P0[(size_t)j1 * ND + col] * a[2] - P1[(size_t)j1 * ND + col] * a[3];
        u32 pk = (u32)f2bf(rw0) | ((u32)f2bf(rw1) << 16);
        *(u32*)&C1[((size_t)b * N + col) * (M / 2) + j0] = pk;
      } else {
        // EPI 2: rows=d, cols=j. DltT[b][d][2j]=dre, [2j+1]=dim
        float alpha = ((col == 0) ? 1.0f : 2.0f) * (1.0f / 2048.0f);
#pragma unroll
        for (int q = 0; q < 4; q++) {
          int dd = row0 + q;
          u32 reim = *(const u32*)&C1[((size_t)b * M + dd) * 512 + 2 * col];
          float xr = bf2f((unsigned short)(reim & 0xffffu));
          float xi = bf2f((unsigned short)(reim >> 16));
          float mcv = P0[(size_t)dd * 256 + col];
          float msv = P1[(size_t)dd * 256 + col];
          float m1 = mcv - 1.0f;
          float dre = alpha * (m1 * xr - msv * xi + 0.1f * a[q]);
          float dim = alpha * (msv * xr + m1 * xi);
          u32 pk = (u32)f2bf(dre) | ((u32)f2bf(dim) << 16);
          *(u32*)&C0[((size_t)b * M + dd) * 512 + 2 * col] = pk;
        }
      }
    }
  }
}

// ---------------- K4: y = 2x + corr(bf16), LayerNorm over D ----------------
__global__ __launch_bounds__(256) void k4_ln(const float* __restrict__ x,
                                             const unsigned short* __restrict__ corr,
                                             const float* __restrict__ g,
                                             const float* __restrict__ be,
                                             float* __restrict__ out) {
  int row = blockIdx.x;
  int t = threadIdx.x;
  size_t base = (size_t)row * ND + t * 4;
  u16x4 cv = *(const u16x4*)&corr[base];
  float4 xv = *(const float4*)&x[base];
  float v[4] = {fmaf(2.f, xv.x, bf2f(cv[0])), fmaf(2.f, xv.y, bf2f(cv[1])),
                fmaf(2.f, xv.z, bf2f(cv[2])), fmaf(2.f, xv.w, bf2f(cv[3]))};
  float s = v[0] + v[1] + v[2] + v[3];
  float q = v[0] * v[0] + v[1] * v[1] + v[2] * v[2] + v[3] * v[3];
#pragma unroll
  for (int o = 32; o >= 1; o >>= 1) {
    s += __shfl_xor(s, o, 64);
    q += __shfl_xor(q, o, 64);
  }
  __shared__ float ss[4], qs[4];
  if ((t & 63) == 0) { ss[t >> 6] = s; qs[t >> 6] = q; }
  __syncthreads();
  s = ss[0] + ss[1] + ss[2] + ss[3];
  q = qs[0] + qs[1] + qs[2] + qs[3];
  float mu = s * (1.0f / (float)ND);
  float var = q * (1.0f / (float)ND) - mu * mu;
  float rstd = rsqrtf(var + 1e-5f);
  float4 gv = *(const float4*)&g[t * 4];
  float4 bv = *(const float4*)&be[t * 4];
  float4 ov;
  ov.x = (v[0] - mu) * rstd * gv.x + bv.x;
  ov.y = (v[1] - mu) * rstd * gv.y + bv.y;
  ov.z = (v[2] - mu) * rstd * gv.z + bv.z;
  ov.w = (v[3] - mu) * rstd * gv.w + bv.w;
  *(float4*)&out[base] = ov;
}

extern "C" void kernel_launch(void* const* d_in, const int* in_sizes, int n_in,
                              void* d_out, int out_size, void* d_ws, size_t ws_size,
                              hipStream_t stream) {
  const float* x   = (const float*)d_in[0];
  const float* mag = (const float*)d_in[1];
  const float* ph  = (const float*)d_in[2];
  const float* W   = (const float*)d_in[3];
  const float* g   = (const float*)d_in[4];
  const float* be  = (const float*)d_in[5];
  float* out = (float*)d_out;
  char* w = (char*)d_ws;

  float*          master = (float*)(w);                          // 8 KB
  unsigned short* CFi    = (unsigned short*)(w + (1ull << 20));  // 2 MB [512][2048]
  unsigned short* CSi    = (unsigned short*)(w + (3ull << 20));  // 2 MB [2048][512]
  float*          mc     = (float*)(w + (5ull << 20));           // 1 MB [k][d]
  float*          ms     = (float*)(w + (6ull << 20));           // 1 MB
  float*          mcT    = (float*)(w + (7ull << 20));           // 1 MB [d][k]
  float*          msT    = (float*)(w + (8ull << 20));           // 1 MB
  unsigned short* WT     = (unsigned short*)(w + (9ull << 20));  // 128 KB [j][k]
  unsigned short* XqT    = (unsigned short*)(w + (10ull << 20)); // 8 MB [b][d][512] ilv
  unsigned short* RXwT   = (unsigned short*)(w + (18ull << 20)); // 4 MB [b][d][256]
  unsigned short* DltT   = (unsigned short*)(w + (22ull << 20)); // 8 MB [b][d][512] ilv
  unsigned short* corr   = (unsigned short*)(w + (30ull << 20)); // 32 MB [b][s][d]
  unsigned short* xt     = (unsigned short*)(w + (62ull << 20)); // 32 MB [b][d][s]

  k_master<<<8, 256, 0, stream>>>(master);
  k_tabs<<<8192, 256, 0, stream>>>(master, CFi, CSi);
  k_cw2<<<64, 256, 0, stream>>>(mag, ph, mc, ms, mcT, msT);
  k_wt<<<16, 256, 0, stream>>>(W, WT);
  k_conv<<<4096, 256, 0, stream>>>(x, xt);
  // forward DFT + ReXw fusion: XqT[b][d][512] ilv, RXwT[b][d][256]
  gemm_db<128, 64, 1><<<512, 256, 0, stream>>>(CFi, xt, XqT, RXwT, mc, ms,
                                               512, 1024, 2048, 0,
                                               (size_t)1024 * 2048);
  // interference + delta fusion: DltT[b][d][512] ilv
  gemm_db<128, 64, 2><<<256, 256, 0, stream>>>(RXwT, WT, DltT, XqT, mcT, msT,
                                               1024, 256, 256,
                                               (size_t)1024 * 256, 0);
  // synthesis: corr[b][s][d]
  gemm_db<128, 128, 0><<<1024, 256, 0, stream>>>(CSi, DltT, corr, nullptr,
                                                 nullptr, nullptr,
                                                 2048, 1024, 512, 0,
                                                 (size_t)1024 * 512);
  k4_ln<<<16384, 256, 0, stream>>>(x, corr, g, be, out);
}